// Round 1
// baseline (425.696 us; speedup 1.0000x reference)
//
#include <hip/hip_runtime.h>
#include <hip/hip_bf16.h>

#define B_ 16
#define N_ 1024
#define H_ 256
#define HEADS_ 8
#define DH_ 32
#define BN_ (B_*N_)
#define F_ (2*H_)      // 512
#define QKV_ 768
#define SROW 1032      // padded LDS row stride (elems) for scores

typedef __attribute__((ext_vector_type(8))) __bf16 bf16x8;
typedef __attribute__((ext_vector_type(4))) float floatx4;

__device__ __forceinline__ unsigned short f2bf(float f) {
    union { float f; unsigned int u; } c; c.f = f;
    unsigned int u = c.u;
    return (unsigned short)((u + 0x7fffu + ((u >> 16) & 1u)) >> 16);
}
__device__ __forceinline__ float bf2f(unsigned short s) {
    union { unsigned int u; float f; } c; c.u = ((unsigned int)s) << 16;
    return c.f;
}
__device__ __forceinline__ __bf16 us2bf(unsigned short u) {
    union { unsigned short u; __bf16 b; } c; c.u = u; return c.b;
}

// ---------------- kernel 1: fused dual LayerNorm -> f (bf16 [BN][512]) ----
__global__ __launch_bounds__(64) void ln_kernel(
        const float* __restrict__ xs_g, const float* __restrict__ xo_g,
        const float* __restrict__ gs, const float* __restrict__ bs,
        const float* __restrict__ go, const float* __restrict__ bo,
        unsigned short* __restrict__ f) {
    int row = blockIdx.x;
    int t = threadIdx.x;
    const float4 vs = ((const float4*)(xs_g + (size_t)row * H_))[t];
    const float4 vo = ((const float4*)(xo_g + (size_t)row * H_))[t];
    float s1 = vs.x + vs.y + vs.z + vs.w;
    float s2 = vs.x*vs.x + vs.y*vs.y + vs.z*vs.z + vs.w*vs.w;
    float o1 = vo.x + vo.y + vo.z + vo.w;
    float o2 = vo.x*vo.x + vo.y*vo.y + vo.z*vo.z + vo.w*vo.w;
    #pragma unroll
    for (int m = 1; m < 64; m <<= 1) {
        s1 += __shfl_xor(s1, m); s2 += __shfl_xor(s2, m);
        o1 += __shfl_xor(o1, m); o2 += __shfl_xor(o2, m);
    }
    const float inv = 1.0f / 256.0f;
    float ms = s1 * inv, vvs = s2 * inv - ms * ms;
    float mo = o1 * inv, vvo = o2 * inv - mo * mo;
    float rs = rsqrtf(vvs + 1e-5f);
    float ro = rsqrtf(vvo + 1e-5f);
    float4 g4s = ((const float4*)gs)[t];
    float4 b4s = ((const float4*)bs)[t];
    float4 g4o = ((const float4*)go)[t];
    float4 b4o = ((const float4*)bo)[t];
    ushort4 os, oo;
    os.x = f2bf((vs.x - ms) * rs * g4s.x + b4s.x);
    os.y = f2bf((vs.y - ms) * rs * g4s.y + b4s.y);
    os.z = f2bf((vs.z - ms) * rs * g4s.z + b4s.z);
    os.w = f2bf((vs.w - ms) * rs * g4s.w + b4s.w);
    oo.x = f2bf((vo.x - mo) * ro * g4o.x + b4o.x);
    oo.y = f2bf((vo.y - mo) * ro * g4o.y + b4o.y);
    oo.z = f2bf((vo.z - mo) * ro * g4o.z + b4o.z);
    oo.w = f2bf((vo.w - mo) * ro * g4o.w + b4o.w);
    *(ushort4*)(f + (size_t)row * F_ + 4 * t) = os;
    *(ushort4*)(f + (size_t)row * F_ + H_ + 4 * t) = oo;
}

// ---------------- kernel 2: pack transposed bf16 weights ------------------
__global__ __launch_bounds__(256) void pack_w(
        const float* __restrict__ Wq, const float* __restrict__ Wk,
        const float* __restrict__ Wv, const float* __restrict__ Wo,
        unsigned short* __restrict__ WcT, unsigned short* __restrict__ WoT) {
    int i = blockIdx.x * 256 + threadIdx.x;
    const int total1 = QKV_ * F_;   // WcT[n][k], n<768, k<512
    if (i < total1) {
        int n = i / F_, k = i % F_;
        float w;
        if (n < 256)      w = Wq[(size_t)k * H_ + n];
        else if (n < 512) w = Wk[(size_t)k * H_ + (n - 256)];
        else              w = Wv[(size_t)k * H_ + (n - 512)];
        WcT[i] = f2bf(w);
    }
    const int total2 = H_ * H_;     // WoT[n][k]
    if (i < total2) {
        int n = i / H_, k = i % H_;
        WoT[i] = f2bf(Wo[(size_t)k * H_ + n]);
    }
}

// ---------------- kernel 3: QKV GEMM  qkv[BN][768] = f @ WcT^T ------------
// one wave -> one 16x16 output tile; K = 512 -> 16 MFMA
__global__ __launch_bounds__(256) void qkv_gemm(
        const unsigned short* __restrict__ f,
        const unsigned short* __restrict__ WcT,
        unsigned short* __restrict__ qkv) {
    int wave = blockIdx.x * 4 + (threadIdx.x >> 6);
    int lane = threadIdx.x & 63;
    int ni = wave % (QKV_ / 16);
    int mi = wave / (QKV_ / 16);
    int m0 = mi * 16, n0 = ni * 16;
    int r = lane & 15, q = lane >> 4;
    const bf16x8* ap = (const bf16x8*)(f   + (size_t)(m0 + r) * F_ + q * 8);
    const bf16x8* bp = (const bf16x8*)(WcT + (size_t)(n0 + r) * F_ + q * 8);
    floatx4 acc = {0.f, 0.f, 0.f, 0.f};
    #pragma unroll
    for (int k = 0; k < F_ / 32; ++k) {
        acc = __builtin_amdgcn_mfma_f32_16x16x32_bf16(ap[k * 4], bp[k * 4], acc, 0, 0, 0);
    }
    #pragma unroll
    for (int i = 0; i < 4; ++i) {
        int rowg = m0 + q * 4 + i;               // C row = quad*4+reg
        qkv[(size_t)rowg * QKV_ + n0 + r] = f2bf(acc[i]);  // C col = lane&15
    }
}

// ---------------- kernel 4: attention (per b,h, 16-row q tile) ------------
__global__ __launch_bounds__(256) void attn(
        const unsigned short* __restrict__ qkv,
        unsigned short* __restrict__ msg) {
    __shared__ __align__(16) unsigned short sc[16 * SROW];  // 33 KB scores
    __shared__ float part[4][16][32];                        // 8 KB PV partials
    __shared__ float rinv[16];
    int blk = blockIdx.x;
    int qt = blk & 63;
    int h  = (blk >> 6) & 7;
    int b  = blk >> 9;
    int t = threadIdx.x;
    int w = t >> 6, lane = t & 63;
    int r = lane & 15, qd = lane >> 4;
    int q0 = qt * 16;
    const unsigned short* base = qkv + (size_t)b * N_ * QKV_;
    // Q fragment: A[m=lane&15][k=quad*8+j]
    bf16x8 qf = *(const bf16x8*)(base + (size_t)(q0 + r) * QKV_ + h * DH_ + qd * 8);
    const float scale = 0.17677669529663687f;  // 1/sqrt(32)
    // ---- S = Q K^T, each wave does 16 of the 64 key tiles
    for (int kt = w * 16; kt < w * 16 + 16; ++kt) {
        bf16x8 kf = *(const bf16x8*)(base + (size_t)(kt * 16 + r) * QKV_ + H_ + h * DH_ + qd * 8);
        floatx4 s = {0.f, 0.f, 0.f, 0.f};
        s = __builtin_amdgcn_mfma_f32_16x16x32_bf16(qf, kf, s, 0, 0, 0);
        #pragma unroll
        for (int i = 0; i < 4; ++i)
            sc[(qd * 4 + i) * SROW + kt * 16 + r] = f2bf(s[i] * scale);
    }
    __syncthreads();
    // ---- softmax over full 1024-row; store unnormalized exp, keep 1/sum
    {
        int rr = t >> 4, li = t & 15;
        float mxv = -1e30f;
        for (int i = 0; i < 64; ++i)
            mxv = fmaxf(mxv, bf2f(sc[rr * SROW + li + 16 * i]));
        #pragma unroll
        for (int m = 1; m < 16; m <<= 1) mxv = fmaxf(mxv, __shfl_xor(mxv, m));
        float sum = 0.f;
        for (int i = 0; i < 64; ++i) {
            int idx = rr * SROW + li + 16 * i;
            float e = __expf(bf2f(sc[idx]) - mxv);
            sum += e;
            sc[idx] = f2bf(e);
        }
        #pragma unroll
        for (int m = 1; m < 16; m <<= 1) sum += __shfl_xor(sum, m);
        if (li == 0) rinv[rr] = 1.0f / sum;
    }
    __syncthreads();
    // ---- PV: each wave handles 256 of the K=1024 contraction
    floatx4 acc0 = {0.f,0.f,0.f,0.f}, acc1 = {0.f,0.f,0.f,0.f};
    for (int s = 0; s < 8; ++s) {
        int k0 = w * 256 + s * 32;
        bf16x8 pf = *(const bf16x8*)(sc + r * SROW + k0 + qd * 8);
        bf16x8 v0, v1;
        #pragma unroll
        for (int j = 0; j < 8; ++j) {
            int kk = k0 + qd * 8 + j;
            const unsigned short* vp = base + (size_t)kk * QKV_ + F_ + h * DH_;
            v0[j] = us2bf(vp[r]);
            v1[j] = us2bf(vp[16 + r]);
        }
        acc0 = __builtin_amdgcn_mfma_f32_16x16x32_bf16(pf, v0, acc0, 0, 0, 0);
        acc1 = __builtin_amdgcn_mfma_f32_16x16x32_bf16(pf, v1, acc1, 0, 0, 0);
    }
    #pragma unroll
    for (int i = 0; i < 4; ++i) {
        part[w][qd * 4 + i][r]      = acc0[i];
        part[w][qd * 4 + i][16 + r] = acc1[i];
    }
    __syncthreads();
    for (int e = t; e < 512; e += 256) {
        int row = e >> 5, col = e & 31;
        float v = part[0][row][col] + part[1][row][col] + part[2][row][col] + part[3][row][col];
        v *= rinv[row];
        msg[((size_t)(b * N_ + q0 + row)) * H_ + h * DH_ + col] = f2bf(v);
    }
}

// ---------------- kernel 5: Wo GEMM + residual ----------------------------
__global__ __launch_bounds__(256) void out_gemm(
        const unsigned short* __restrict__ msg,
        const unsigned short* __restrict__ WoT,
        const float* __restrict__ x_out,
        float* __restrict__ outx, float* __restrict__ mxf) {
    int wave = blockIdx.x * 4 + (threadIdx.x >> 6);
    int lane = threadIdx.x & 63;
    int ni = wave & 15;
    int mi = wave >> 4;
    int m0 = mi * 16, n0 = ni * 16;
    int r = lane & 15, q = lane >> 4;
    const bf16x8* ap = (const bf16x8*)(msg + (size_t)(m0 + r) * H_ + q * 8);
    const bf16x8* bp = (const bf16x8*)(WoT + (size_t)(n0 + r) * H_ + q * 8);
    floatx4 acc = {0.f, 0.f, 0.f, 0.f};
    #pragma unroll
    for (int k = 0; k < H_ / 32; ++k) {
        acc = __builtin_amdgcn_mfma_f32_16x16x32_bf16(ap[k * 4], bp[k * 4], acc, 0, 0, 0);
    }
    #pragma unroll
    for (int i = 0; i < 4; ++i) {
        int rowg = m0 + q * 4 + i;
        int colg = n0 + r;
        float v = acc[i];
        size_t idx = (size_t)rowg * H_ + colg;
        outx[idx] = x_out[idx] + v;
        mxf[idx] = v;
    }
}

// ---------------- kernel 6: position head  p = m_x @ Wp -------------------
__global__ __launch_bounds__(64) void p_kernel(
        const float* __restrict__ mxf, const float* __restrict__ Wp,
        float* __restrict__ outp) {
    int row = blockIdx.x;
    int t = threadIdx.x;
    float a0 = 0.f, a1 = 0.f, a2 = 0.f;
    #pragma unroll
    for (int i = 0; i < 4; ++i) {
        int c = t + 64 * i;
        float v = mxf[(size_t)row * H_ + c];
        a0 += v * Wp[c * 3 + 0];
        a1 += v * Wp[c * 3 + 1];
        a2 += v * Wp[c * 3 + 2];
    }
    #pragma unroll
    for (int m = 1; m < 64; m <<= 1) {
        a0 += __shfl_xor(a0, m); a1 += __shfl_xor(a1, m); a2 += __shfl_xor(a2, m);
    }
    if (t == 0) {
        outp[(size_t)row * 3 + 0] = a0;
        outp[(size_t)row * 3 + 1] = a1;
        outp[(size_t)row * 3 + 2] = a2;
    }
}

extern "C" void kernel_launch(void* const* d_in, const int* in_sizes, int n_in,
                              void* d_out, int out_size, void* d_ws, size_t ws_size,
                              hipStream_t stream) {
    const float* x_source = (const float*)d_in[0];
    // d_in[1] = p_source (unused by reference)
    const float* x_out = (const float*)d_in[2];
    // d_in[3] = p_out (unused by reference)
    const float* g_s = (const float*)d_in[4];
    const float* b_s = (const float*)d_in[5];
    const float* g_o = (const float*)d_in[6];
    const float* b_o = (const float*)d_in[7];
    const float* Wq = (const float*)d_in[8];
    const float* Wk = (const float*)d_in[9];
    const float* Wv = (const float*)d_in[10];
    const float* Wo = (const float*)d_in[11];
    const float* Wp = (const float*)d_in[12];

    float* outx = (float*)d_out;                  // [BN][256]
    float* outp = outx + (size_t)BN_ * H_;        // [BN][3]

    char* ws = (char*)d_ws;
    unsigned short* f_buf = (unsigned short*)(ws);                       // 16.78 MB
    unsigned short* WcT   = (unsigned short*)(ws + 16777216);            // 0.79 MB
    unsigned short* WoT   = (unsigned short*)(ws + 17563648);            // 0.13 MB
    unsigned short* qkv   = (unsigned short*)(ws + 17694720);            // 25.17 MB
    unsigned short* msg   = (unsigned short*)(ws + 42860544);            // 8.39 MB
    float*          mxf   = (float*)         (ws + 51249152);            // 16.78 MB

    ln_kernel<<<BN_, 64, 0, stream>>>(x_source, x_out, g_s, b_s, g_o, b_o, f_buf);
    pack_w<<<(QKV_ * F_ + 255) / 256, 256, 0, stream>>>(Wq, Wk, Wv, Wo, WcT, WoT);
    qkv_gemm<<<(BN_ / 16) * (QKV_ / 16) / 4, 256, 0, stream>>>(f_buf, WcT, qkv);
    attn<<<B_ * HEADS_ * (N_ / 16), 256, 0, stream>>>(qkv, msg);
    out_gemm<<<(BN_ / 16) * (H_ / 16) / 4, 256, 0, stream>>>(msg, WoT, x_out, outx, mxf);
    p_kernel<<<BN_, 64, 0, stream>>>(mxf, Wp, outp);
}

// Round 2
// 261.272 us; speedup vs baseline: 1.6293x; 1.6293x over previous
//
#include <hip/hip_runtime.h>
#include <hip/hip_bf16.h>

#define B_ 16
#define N_ 1024
#define H_ 256
#define HEADS_ 8
#define DH_ 32
#define BN_ (B_*N_)
#define F_ (2*H_)      // 512
#define QKV_ 768
#define SROW 1032      // padded LDS row stride (elems) for scores

typedef __attribute__((ext_vector_type(8))) __bf16 bf16x8;
typedef __attribute__((ext_vector_type(4))) float floatx4;

__device__ __forceinline__ unsigned short f2bf(float f) {
    union { float f; unsigned int u; } c; c.f = f;
    unsigned int u = c.u;
    return (unsigned short)((u + 0x7fffu + ((u >> 16) & 1u)) >> 16);
}
__device__ __forceinline__ float bf2f(unsigned short s) {
    union { unsigned int u; float f; } c; c.u = ((unsigned int)s) << 16;
    return c.f;
}

// async global->LDS, 16B per lane; lds dest = wave-uniform base + lane*16
__device__ __forceinline__ void async16(const void* g, void* l) {
    __builtin_amdgcn_global_load_lds(
        (const __attribute__((address_space(1))) unsigned int*)g,
        (__attribute__((address_space(3))) unsigned int*)l,
        16, 0, 0);
}

// ---------------- kernel 1: fused dual LayerNorm -> f (bf16 [BN][512]) ----
__global__ __launch_bounds__(64) void ln_kernel(
        const float* __restrict__ xs_g, const float* __restrict__ xo_g,
        const float* __restrict__ gs, const float* __restrict__ bs,
        const float* __restrict__ go, const float* __restrict__ bo,
        unsigned short* __restrict__ f) {
    int row = blockIdx.x;
    int t = threadIdx.x;
    const float4 vs = ((const float4*)(xs_g + (size_t)row * H_))[t];
    const float4 vo = ((const float4*)(xo_g + (size_t)row * H_))[t];
    float s1 = vs.x + vs.y + vs.z + vs.w;
    float s2 = vs.x*vs.x + vs.y*vs.y + vs.z*vs.z + vs.w*vs.w;
    float o1 = vo.x + vo.y + vo.z + vo.w;
    float o2 = vo.x*vo.x + vo.y*vo.y + vo.z*vo.z + vo.w*vo.w;
    #pragma unroll
    for (int m = 1; m < 64; m <<= 1) {
        s1 += __shfl_xor(s1, m); s2 += __shfl_xor(s2, m);
        o1 += __shfl_xor(o1, m); o2 += __shfl_xor(o2, m);
    }
    const float inv = 1.0f / 256.0f;
    float ms = s1 * inv, vvs = s2 * inv - ms * ms;
    float mo = o1 * inv, vvo = o2 * inv - mo * mo;
    float rs = rsqrtf(vvs + 1e-5f);
    float ro = rsqrtf(vvo + 1e-5f);
    float4 g4s = ((const float4*)gs)[t];
    float4 b4s = ((const float4*)bs)[t];
    float4 g4o = ((const float4*)go)[t];
    float4 b4o = ((const float4*)bo)[t];
    ushort4 os, oo;
    os.x = f2bf((vs.x - ms) * rs * g4s.x + b4s.x);
    os.y = f2bf((vs.y - ms) * rs * g4s.y + b4s.y);
    os.z = f2bf((vs.z - ms) * rs * g4s.z + b4s.z);
    os.w = f2bf((vs.w - ms) * rs * g4s.w + b4s.w);
    oo.x = f2bf((vo.x - mo) * ro * g4o.x + b4o.x);
    oo.y = f2bf((vo.y - mo) * ro * g4o.y + b4o.y);
    oo.z = f2bf((vo.z - mo) * ro * g4o.z + b4o.z);
    oo.w = f2bf((vo.w - mo) * ro * g4o.w + b4o.w);
    *(ushort4*)(f + (size_t)row * F_ + 4 * t) = os;
    *(ushort4*)(f + (size_t)row * F_ + H_ + 4 * t) = oo;
}

// ---------------- kernel 2: pack weights + fold Wo@Wp ---------------------
__global__ __launch_bounds__(256) void pack_w(
        const float* __restrict__ Wq, const float* __restrict__ Wk,
        const float* __restrict__ Wv, const float* __restrict__ Wo,
        const float* __restrict__ Wp,
        unsigned short* __restrict__ WcT, unsigned short* __restrict__ WoT,
        float* __restrict__ WoP) {
    int i = blockIdx.x * 256 + threadIdx.x;
    const int total1 = QKV_ * F_;   // WcT[n][k], n<768, k<512
    if (i < total1) {
        int n = i / F_, k = i % F_;
        float w;
        if (n < 256)      w = Wq[(size_t)k * H_ + n];
        else if (n < 512) w = Wk[(size_t)k * H_ + (n - 256)];
        else              w = Wv[(size_t)k * H_ + (n - 512)];
        WcT[i] = f2bf(w);
    }
    const int total2 = H_ * H_;     // WoT[n][k]
    if (i < total2) {
        int n = i / H_, k = i % H_;
        WoT[i] = f2bf(Wo[(size_t)k * H_ + n]);
    }
    if (i < H_ * 3) {               // WoP[c][j] = sum_n Wo[c][n] * Wp[n][j]
        int c = i / 3, j = i % 3;
        float s = 0.f;
        for (int n = 0; n < H_; ++n) s += Wo[(size_t)c * H_ + n] * Wp[n * 3 + j];
        WoP[i] = s;
    }
}

// ---------------- kernel 3: QKV GEMM (128x128 LDS tile) -------------------
// C[16384][768] = f @ WcT^T, scattered into head-major q, k, and vT buffers
__global__ __launch_bounds__(256) void qkv_gemm(
        const unsigned short* __restrict__ f,
        const unsigned short* __restrict__ WcT,
        unsigned short* __restrict__ qb,
        unsigned short* __restrict__ kb,
        unsigned short* __restrict__ vT) {
    __shared__ __align__(16) unsigned short As[128 * 32];
    __shared__ __align__(16) unsigned short Bs[128 * 32];
    int t = threadIdx.x;
    int w = t >> 6, lane = t & 63;
    int r = lane & 15, qd = lane >> 4;
    int wm = (w >> 1) * 64, wn = (w & 1) * 64;
    int m0 = blockIdx.y * 128, n0 = blockIdx.x * 128;
    int lrow = lane >> 2, lcol = (lane & 3) * 8;
    floatx4 acc[4][4] = {};
    const unsigned short* gA = f   + (size_t)(m0 + w * 32 + lrow) * F_ + lcol;
    const unsigned short* gB = WcT + (size_t)(n0 + w * 32 + lrow) * F_ + lcol;
    unsigned short* lA = As + (w * 32) * 32;
    unsigned short* lB = Bs + (w * 32) * 32;
    for (int k0 = 0; k0 < F_; k0 += 32) {
        async16(gA + k0,            lA);
        async16(gA + k0 + 16 * F_,  lA + 16 * 32);
        async16(gB + k0,            lB);
        async16(gB + k0 + 16 * F_,  lB + 16 * 32);
        __syncthreads();
        bf16x8 aF[4], bF[4];
        #pragma unroll
        for (int mt = 0; mt < 4; ++mt)
            aF[mt] = *(const bf16x8*)(As + (wm + mt * 16 + r) * 32 + qd * 8);
        #pragma unroll
        for (int nt = 0; nt < 4; ++nt)
            bF[nt] = *(const bf16x8*)(Bs + (wn + nt * 16 + r) * 32 + qd * 8);
        #pragma unroll
        for (int mt = 0; mt < 4; ++mt)
            #pragma unroll
            for (int nt = 0; nt < 4; ++nt)
                acc[mt][nt] = __builtin_amdgcn_mfma_f32_16x16x32_bf16(aF[mt], bF[nt], acc[mt][nt], 0, 0, 0);
        __syncthreads();
    }
    // scatter epilogue: col decides q/k/v; head-major layouts
    #pragma unroll
    for (int nt = 0; nt < 4; ++nt) {
        int cg = n0 + wn + nt * 16 + r;
        int sec = cg >> 8;              // 0=q 1=k 2=v (uniform per subtile)
        int hh = (cg >> 5) & 7;
        int d = cg & 31;
        #pragma unroll
        for (int mt = 0; mt < 4; ++mt) {
            int tok = m0 + wm + mt * 16 + qd * 4;
            int b = tok >> 10, tl = tok & 1023;
            size_t hb = (size_t)b * 8 + hh;
            if (sec == 0) {
                unsigned short* p = qb + (hb * 1024 + tl) * 32 + d;
                #pragma unroll
                for (int i = 0; i < 4; ++i) p[i * 32] = f2bf(acc[mt][nt][i]);
            } else if (sec == 1) {
                unsigned short* p = kb + (hb * 1024 + tl) * 32 + d;
                #pragma unroll
                for (int i = 0; i < 4; ++i) p[i * 32] = f2bf(acc[mt][nt][i]);
            } else {
                ushort4 v4;
                v4.x = f2bf(acc[mt][nt][0]); v4.y = f2bf(acc[mt][nt][1]);
                v4.z = f2bf(acc[mt][nt][2]); v4.w = f2bf(acc[mt][nt][3]);
                *(ushort4*)(vT + (hb * 32 + d) * 1024 + tl) = v4;
            }
        }
    }
}

// ---------------- kernel 4: attention (per b,h, 16-row q tile) ------------
// q,k: [B*H][N][32] ; vT: [B*H][32][N]
__global__ __launch_bounds__(256) void attn(
        const unsigned short* __restrict__ qb,
        const unsigned short* __restrict__ kb,
        const unsigned short* __restrict__ vT,
        unsigned short* __restrict__ msg) {
    __shared__ __align__(16) unsigned short sc[16 * SROW];
    __shared__ float part[4][16][32];
    __shared__ float rinv[16];
    int blk = blockIdx.x;
    int qt = blk & 63;
    int h  = (blk >> 6) & 7;
    int b  = blk >> 9;
    int t = threadIdx.x;
    int w = t >> 6, lane = t & 63;
    int r = lane & 15, qd = lane >> 4;
    int q0 = qt * 16;
    size_t hb = (size_t)b * 8 + h;
    const unsigned short* qs = qb + hb * (1024 * 32);
    const unsigned short* ks = kb + hb * (1024 * 32);
    const unsigned short* vs = vT + hb * (32 * 1024);
    bf16x8 qf = *(const bf16x8*)(qs + (size_t)(q0 + r) * 32 + qd * 8);
    const float scale = 0.17677669529663687f;  // 1/sqrt(32)
    // ---- S = Q K^T
    for (int kt = w * 16; kt < w * 16 + 16; ++kt) {
        bf16x8 kf = *(const bf16x8*)(ks + (size_t)(kt * 16 + r) * 32 + qd * 8);
        floatx4 s = {0.f, 0.f, 0.f, 0.f};
        s = __builtin_amdgcn_mfma_f32_16x16x32_bf16(qf, kf, s, 0, 0, 0);
        #pragma unroll
        for (int i = 0; i < 4; ++i)
            sc[(qd * 4 + i) * SROW + kt * 16 + r] = f2bf(s[i] * scale);
    }
    __syncthreads();
    // ---- full-row softmax; store unnormalized exp, keep 1/sum
    {
        int rr = t >> 4, li = t & 15;
        float mxv = -1e30f;
        for (int i = 0; i < 64; ++i)
            mxv = fmaxf(mxv, bf2f(sc[rr * SROW + li + 16 * i]));
        #pragma unroll
        for (int m = 1; m < 16; m <<= 1) mxv = fmaxf(mxv, __shfl_xor(mxv, m));
        float sum = 0.f;
        for (int i = 0; i < 64; ++i) {
            int idx = rr * SROW + li + 16 * i;
            float e = __expf(bf2f(sc[idx]) - mxv);
            sum += e;
            sc[idx] = f2bf(e);
        }
        #pragma unroll
        for (int m = 1; m < 16; m <<= 1) sum += __shfl_xor(sum, m);
        if (li == 0) rinv[rr] = 1.0f / sum;
    }
    __syncthreads();
    // ---- PV: each wave handles 256 of the K=1024 contraction
    floatx4 acc0 = {0.f,0.f,0.f,0.f}, acc1 = {0.f,0.f,0.f,0.f};
    #pragma unroll
    for (int s = 0; s < 8; ++s) {
        int k0 = w * 256 + s * 32;
        bf16x8 pf = *(const bf16x8*)(sc + r * SROW + k0 + qd * 8);
        bf16x8 v0 = *(const bf16x8*)(vs + (size_t)r * 1024 + k0 + qd * 8);
        bf16x8 v1 = *(const bf16x8*)(vs + (size_t)(16 + r) * 1024 + k0 + qd * 8);
        acc0 = __builtin_amdgcn_mfma_f32_16x16x32_bf16(pf, v0, acc0, 0, 0, 0);
        acc1 = __builtin_amdgcn_mfma_f32_16x16x32_bf16(pf, v1, acc1, 0, 0, 0);
    }
    #pragma unroll
    for (int i = 0; i < 4; ++i) {
        part[w][qd * 4 + i][r]      = acc0[i];
        part[w][qd * 4 + i][16 + r] = acc1[i];
    }
    __syncthreads();
    for (int e = t; e < 512; e += 256) {
        int row = e >> 5, col = e & 31;
        float v = part[0][row][col] + part[1][row][col] + part[2][row][col] + part[3][row][col];
        v *= rinv[row];
        msg[((size_t)(b * N_ + q0 + row)) * H_ + h * DH_ + col] = f2bf(v);
    }
}

// ---------------- kernel 5: Wo GEMM + residual (128x128 LDS tile) ---------
__global__ __launch_bounds__(256) void out_gemm(
        const unsigned short* __restrict__ msg,
        const unsigned short* __restrict__ WoT,
        const float* __restrict__ x_out,
        float* __restrict__ outx) {
    __shared__ __align__(16) unsigned short As[128 * 32];
    __shared__ __align__(16) unsigned short Bs[128 * 32];
    int t = threadIdx.x;
    int w = t >> 6, lane = t & 63;
    int r = lane & 15, qd = lane >> 4;
    int wm = (w >> 1) * 64, wn = (w & 1) * 64;
    int m0 = blockIdx.y * 128, n0 = blockIdx.x * 128;
    int lrow = lane >> 2, lcol = (lane & 3) * 8;
    floatx4 acc[4][4] = {};
    const unsigned short* gA = msg + (size_t)(m0 + w * 32 + lrow) * H_ + lcol;
    const unsigned short* gB = WoT + (size_t)(n0 + w * 32 + lrow) * H_ + lcol;
    unsigned short* lA = As + (w * 32) * 32;
    unsigned short* lB = Bs + (w * 32) * 32;
    for (int k0 = 0; k0 < H_; k0 += 32) {
        async16(gA + k0,           lA);
        async16(gA + k0 + 16 * H_, lA + 16 * 32);
        async16(gB + k0,           lB);
        async16(gB + k0 + 16 * H_, lB + 16 * 32);
        __syncthreads();
        bf16x8 aF[4], bF[4];
        #pragma unroll
        for (int mt = 0; mt < 4; ++mt)
            aF[mt] = *(const bf16x8*)(As + (wm + mt * 16 + r) * 32 + qd * 8);
        #pragma unroll
        for (int nt = 0; nt < 4; ++nt)
            bF[nt] = *(const bf16x8*)(Bs + (wn + nt * 16 + r) * 32 + qd * 8);
        #pragma unroll
        for (int mt = 0; mt < 4; ++mt)
            #pragma unroll
            for (int nt = 0; nt < 4; ++nt)
                acc[mt][nt] = __builtin_amdgcn_mfma_f32_16x16x32_bf16(aF[mt], bF[nt], acc[mt][nt], 0, 0, 0);
        __syncthreads();
    }
    #pragma unroll
    for (int nt = 0; nt < 4; ++nt) {
        int cg = n0 + wn + nt * 16 + r;
        #pragma unroll
        for (int mt = 0; mt < 4; ++mt) {
            int tok = m0 + wm + mt * 16 + qd * 4;
            #pragma unroll
            for (int i = 0; i < 4; ++i) {
                size_t idx = (size_t)(tok + i) * H_ + cg;
                outx[idx] = x_out[idx] + acc[mt][nt][i];
            }
        }
    }
}

// ---------------- kernel 6: position head  p = msg @ WoP ------------------
__global__ __launch_bounds__(64) void p_kernel(
        const unsigned short* __restrict__ msg, const float* __restrict__ WoP,
        float* __restrict__ outp) {
    int row = blockIdx.x;
    int t = threadIdx.x;
    float a0 = 0.f, a1 = 0.f, a2 = 0.f;
    #pragma unroll
    for (int i = 0; i < 4; ++i) {
        int c = t + 64 * i;
        float v = bf2f(msg[(size_t)row * H_ + c]);
        a0 += v * WoP[c * 3 + 0];
        a1 += v * WoP[c * 3 + 1];
        a2 += v * WoP[c * 3 + 2];
    }
    #pragma unroll
    for (int m = 1; m < 64; m <<= 1) {
        a0 += __shfl_xor(a0, m); a1 += __shfl_xor(a1, m); a2 += __shfl_xor(a2, m);
    }
    if (t == 0) {
        outp[(size_t)row * 3 + 0] = a0;
        outp[(size_t)row * 3 + 1] = a1;
        outp[(size_t)row * 3 + 2] = a2;
    }
}

extern "C" void kernel_launch(void* const* d_in, const int* in_sizes, int n_in,
                              void* d_out, int out_size, void* d_ws, size_t ws_size,
                              hipStream_t stream) {
    const float* x_source = (const float*)d_in[0];
    const float* x_out = (const float*)d_in[2];
    const float* g_s = (const float*)d_in[4];
    const float* b_s = (const float*)d_in[5];
    const float* g_o = (const float*)d_in[6];
    const float* b_o = (const float*)d_in[7];
    const float* Wq = (const float*)d_in[8];
    const float* Wk = (const float*)d_in[9];
    const float* Wv = (const float*)d_in[10];
    const float* Wo = (const float*)d_in[11];
    const float* Wp = (const float*)d_in[12];

    float* outx = (float*)d_out;                  // [BN][256]
    float* outp = outx + (size_t)BN_ * H_;        // [BN][3]

    char* ws = (char*)d_ws;
    unsigned short* f_buf = (unsigned short*)(ws);                 // 16.78 MB
    unsigned short* WcT   = (unsigned short*)(ws + 16777216);      // 786 KB
    unsigned short* WoT   = (unsigned short*)(ws + 17563648);      // 131 KB
    float*          WoP   = (float*)         (ws + 17694720);      // 3 KB
    unsigned short* qb    = (unsigned short*)(ws + 17697792);      // 8.39 MB
    unsigned short* kb    = (unsigned short*)(ws + 26086400);      // 8.39 MB
    unsigned short* vT    = (unsigned short*)(ws + 34475008);      // 8.39 MB
    unsigned short* msg   = (unsigned short*)(ws + 42863616);      // 8.39 MB

    ln_kernel<<<BN_, 64, 0, stream>>>(x_source, x_out, g_s, b_s, g_o, b_o, f_buf);
    pack_w<<<(QKV_ * F_ + 255) / 256, 256, 0, stream>>>(Wq, Wk, Wv, Wo, Wp, WcT, WoT, WoP);
    {
        dim3 g(QKV_ / 128, BN_ / 128);
        qkv_gemm<<<g, 256, 0, stream>>>(f_buf, WcT, qb, kb, vT);
    }
    attn<<<B_ * HEADS_ * (N_ / 16), 256, 0, stream>>>(qb, kb, vT, msg);
    {
        dim3 g(H_ / 128, BN_ / 128);
        out_gemm<<<g, 256, 0, stream>>>(msg, WoT, x_out, outx);
    }
    p_kernel<<<BN_, 64, 0, stream>>>(msg, WoP, outp);
}

// Round 3
// 242.499 us; speedup vs baseline: 1.7555x; 1.0774x over previous
//
#include <hip/hip_runtime.h>
#include <hip/hip_bf16.h>

#define B_ 16
#define N_ 1024
#define H_ 256
#define HEADS_ 8
#define DH_ 32
#define BN_ (B_*N_)
#define F_ (2*H_)      // 512
#define QKV_ 768

typedef __attribute__((ext_vector_type(8))) __bf16 bf16x8;
typedef __attribute__((ext_vector_type(4))) float floatx4;

__device__ __forceinline__ unsigned short f2bf(float f) {
    union { float f; unsigned int u; } c; c.f = f;
    unsigned int u = c.u;
    return (unsigned short)((u + 0x7fffu + ((u >> 16) & 1u)) >> 16);
}
__device__ __forceinline__ float bf2f(unsigned short s) {
    union { unsigned int u; float f; } c; c.u = ((unsigned int)s) << 16;
    return c.f;
}
__device__ __forceinline__ unsigned int fbits(float f) {
    union { float f; unsigned int u; } c; c.f = f; return c.u;
}
// pack two floats to bf16x2 (round-to-nearest, ties-away — fine for p in [0,1])
__device__ __forceinline__ unsigned int pk2(float lo, float hi) {
    return ((fbits(lo) + 0x8000u) >> 16) | ((fbits(hi) + 0x8000u) & 0xffff0000u);
}

// async global->LDS, 16B per lane; lds dest = wave-uniform base + lane*16
__device__ __forceinline__ void async16(const void* g, void* l) {
    __builtin_amdgcn_global_load_lds(
        (const __attribute__((address_space(1))) unsigned int*)g,
        (__attribute__((address_space(3))) unsigned int*)l,
        16, 0, 0);
}

// ---------------- kernel 1: fused dual LayerNorm -> f (bf16 [BN][512]) ----
__global__ __launch_bounds__(64) void ln_kernel(
        const float* __restrict__ xs_g, const float* __restrict__ xo_g,
        const float* __restrict__ gs, const float* __restrict__ bs,
        const float* __restrict__ go, const float* __restrict__ bo,
        unsigned short* __restrict__ f) {
    int row = blockIdx.x;
    int t = threadIdx.x;
    const float4 vs = ((const float4*)(xs_g + (size_t)row * H_))[t];
    const float4 vo = ((const float4*)(xo_g + (size_t)row * H_))[t];
    float s1 = vs.x + vs.y + vs.z + vs.w;
    float s2 = vs.x*vs.x + vs.y*vs.y + vs.z*vs.z + vs.w*vs.w;
    float o1 = vo.x + vo.y + vo.z + vo.w;
    float o2 = vo.x*vo.x + vo.y*vo.y + vo.z*vo.z + vo.w*vo.w;
    #pragma unroll
    for (int m = 1; m < 64; m <<= 1) {
        s1 += __shfl_xor(s1, m); s2 += __shfl_xor(s2, m);
        o1 += __shfl_xor(o1, m); o2 += __shfl_xor(o2, m);
    }
    const float inv = 1.0f / 256.0f;
    float ms = s1 * inv, vvs = s2 * inv - ms * ms;
    float mo = o1 * inv, vvo = o2 * inv - mo * mo;
    float rs = rsqrtf(vvs + 1e-5f);
    float ro = rsqrtf(vvo + 1e-5f);
    float4 g4s = ((const float4*)gs)[t];
    float4 b4s = ((const float4*)bs)[t];
    float4 g4o = ((const float4*)go)[t];
    float4 b4o = ((const float4*)bo)[t];
    ushort4 os, oo;
    os.x = f2bf((vs.x - ms) * rs * g4s.x + b4s.x);
    os.y = f2bf((vs.y - ms) * rs * g4s.y + b4s.y);
    os.z = f2bf((vs.z - ms) * rs * g4s.z + b4s.z);
    os.w = f2bf((vs.w - ms) * rs * g4s.w + b4s.w);
    oo.x = f2bf((vo.x - mo) * ro * g4o.x + b4o.x);
    oo.y = f2bf((vo.y - mo) * ro * g4o.y + b4o.y);
    oo.z = f2bf((vo.z - mo) * ro * g4o.z + b4o.z);
    oo.w = f2bf((vo.w - mo) * ro * g4o.w + b4o.w);
    *(ushort4*)(f + (size_t)row * F_ + 4 * t) = os;
    *(ushort4*)(f + (size_t)row * F_ + H_ + 4 * t) = oo;
}

// ---------------- kernel 2: pack weights + fold Wo@Wp ---------------------
__global__ __launch_bounds__(256) void pack_w(
        const float* __restrict__ Wq, const float* __restrict__ Wk,
        const float* __restrict__ Wv, const float* __restrict__ Wo,
        const float* __restrict__ Wp,
        unsigned short* __restrict__ WcT, unsigned short* __restrict__ WoT,
        float* __restrict__ WoP) {
    int i = blockIdx.x * 256 + threadIdx.x;
    const int total1 = QKV_ * F_;   // WcT[n][k], n<768, k<512
    if (i < total1) {
        int n = i / F_, k = i % F_;
        float w;
        if (n < 256)      w = Wq[(size_t)k * H_ + n];
        else if (n < 512) w = Wk[(size_t)k * H_ + (n - 256)];
        else              w = Wv[(size_t)k * H_ + (n - 512)];
        WcT[i] = f2bf(w);
    }
    const int total2 = H_ * H_;     // WoT[n][k]
    if (i < total2) {
        int n = i / H_, k = i % H_;
        WoT[i] = f2bf(Wo[(size_t)k * H_ + n]);
    }
    if (i < H_ * 3) {               // WoP[c][j] = sum_n Wo[c][n] * Wp[n][j]
        int c = i / 3, j = i % 3;
        float s = 0.f;
        for (int n = 0; n < H_; ++n) s += Wo[(size_t)c * H_ + n] * Wp[n * 3 + j];
        WoP[i] = s;
    }
}

// ---------------- kernel 3: QKV GEMM (128x128 LDS tile) -------------------
__global__ __launch_bounds__(256) void qkv_gemm(
        const unsigned short* __restrict__ f,
        const unsigned short* __restrict__ WcT,
        unsigned short* __restrict__ qb,
        unsigned short* __restrict__ kb,
        unsigned short* __restrict__ vT) {
    __shared__ __align__(16) unsigned short As[128 * 32];
    __shared__ __align__(16) unsigned short Bs[128 * 32];
    int t = threadIdx.x;
    int w = t >> 6, lane = t & 63;
    int r = lane & 15, qd = lane >> 4;
    int wm = (w >> 1) * 64, wn = (w & 1) * 64;
    int m0 = blockIdx.y * 128, n0 = blockIdx.x * 128;
    int lrow = lane >> 2, lcol = (lane & 3) * 8;
    floatx4 acc[4][4] = {};
    const unsigned short* gA = f   + (size_t)(m0 + w * 32 + lrow) * F_ + lcol;
    const unsigned short* gB = WcT + (size_t)(n0 + w * 32 + lrow) * F_ + lcol;
    unsigned short* lA = As + (w * 32) * 32;
    unsigned short* lB = Bs + (w * 32) * 32;
    for (int k0 = 0; k0 < F_; k0 += 32) {
        async16(gA + k0,            lA);
        async16(gA + k0 + 16 * F_,  lA + 16 * 32);
        async16(gB + k0,            lB);
        async16(gB + k0 + 16 * F_,  lB + 16 * 32);
        __syncthreads();
        bf16x8 aF[4], bF[4];
        #pragma unroll
        for (int mt = 0; mt < 4; ++mt)
            aF[mt] = *(const bf16x8*)(As + (wm + mt * 16 + r) * 32 + qd * 8);
        #pragma unroll
        for (int nt = 0; nt < 4; ++nt)
            bF[nt] = *(const bf16x8*)(Bs + (wn + nt * 16 + r) * 32 + qd * 8);
        #pragma unroll
        for (int mt = 0; mt < 4; ++mt)
            #pragma unroll
            for (int nt = 0; nt < 4; ++nt)
                acc[mt][nt] = __builtin_amdgcn_mfma_f32_16x16x32_bf16(aF[mt], bF[nt], acc[mt][nt], 0, 0, 0);
        __syncthreads();
    }
    #pragma unroll
    for (int nt = 0; nt < 4; ++nt) {
        int cg = n0 + wn + nt * 16 + r;
        int sec = cg >> 8;              // 0=q 1=k 2=v
        int hh = (cg >> 5) & 7;
        int d = cg & 31;
        #pragma unroll
        for (int mt = 0; mt < 4; ++mt) {
            int tok = m0 + wm + mt * 16 + qd * 4;
            int b = tok >> 10, tl = tok & 1023;
            size_t hb = (size_t)b * 8 + hh;
            if (sec == 0) {
                unsigned short* p = qb + (hb * 1024 + tl) * 32 + d;
                #pragma unroll
                for (int i = 0; i < 4; ++i) p[i * 32] = f2bf(acc[mt][nt][i]);
            } else if (sec == 1) {
                unsigned short* p = kb + (hb * 1024 + tl) * 32 + d;
                #pragma unroll
                for (int i = 0; i < 4; ++i) p[i * 32] = f2bf(acc[mt][nt][i]);
            } else {
                ushort4 v4;
                v4.x = f2bf(acc[mt][nt][0]); v4.y = f2bf(acc[mt][nt][1]);
                v4.z = f2bf(acc[mt][nt][2]); v4.w = f2bf(acc[mt][nt][3]);
                *(ushort4*)(vT + (hb * 32 + d) * 1024 + tl) = v4;
            }
        }
    }
}

// ---------------- kernel 4: flash attention, register-resident ------------
// q,k: [B*H][N][32]; vT: [B*H][32][N]; msg: bf16 [B*N][256]
// grid: B*H*(N/64) blocks x 256; wave w owns q-rows [q0+w*16, +16) x all keys
__global__ __launch_bounds__(256) void attn(
        const unsigned short* __restrict__ qb,
        const unsigned short* __restrict__ kb,
        const unsigned short* __restrict__ vT,
        unsigned short* __restrict__ msg) {
    __shared__ float ob[4][16][33];     // per-wave private O staging
    int blk = blockIdx.x;
    int qt = blk & 15;
    int h  = (blk >> 4) & 7;
    int b  = blk >> 7;
    int t = threadIdx.x;
    int w = t >> 6, lane = t & 63;
    int r = lane & 15, qd = lane >> 4;
    int q0 = qt * 64 + w * 16;
    size_t hb = (size_t)b * 8 + h;
    const unsigned short* qs = qb + hb * (1024 * 32);
    const unsigned short* ks = kb + hb * (1024 * 32);
    const unsigned short* vs = vT + hb * (32 * 1024);
    // Q as B-operand: B[n=q=r][k=qd*8+j]
    bf16x8 qf = *(const bf16x8*)(qs + (size_t)(q0 + r) * 32 + qd * 8);
    const float scale = 0.17677669529663687f;  // 1/sqrt(32)
    floatx4 o0 = {0.f,0.f,0.f,0.f}, o1 = {0.f,0.f,0.f,0.f};
    float mrun = -1e30f, lrun = 0.f;
    int srcA = ((qd & 1) * 2) * 16 + r;
    int srcB = srcA + 16;
    bool hiq = qd >= 2;
    for (int kc = 0; kc < 1024; kc += 32) {
        // S^T tiles: rows = keys kc+qd*4+i (kf0) / kc+16+qd*4+i (kf1), col q=r
        bf16x8 kf0 = *(const bf16x8*)(ks + (size_t)(kc + r) * 32 + qd * 8);
        bf16x8 kf1 = *(const bf16x8*)(ks + (size_t)(kc + 16 + r) * 32 + qd * 8);
        // V^T as A-operand for this k-chunk: A[m=d][k], d-tiles {r, 16+r}
        bf16x8 vf0 = *(const bf16x8*)(vs + (size_t)r * 1024 + kc + qd * 8);
        bf16x8 vf1 = *(const bf16x8*)(vs + (size_t)(16 + r) * 1024 + kc + qd * 8);
        floatx4 s0 = {0.f,0.f,0.f,0.f}, s1 = {0.f,0.f,0.f,0.f};
        s0 = __builtin_amdgcn_mfma_f32_16x16x32_bf16(kf0, qf, s0, 0, 0, 0);
        s1 = __builtin_amdgcn_mfma_f32_16x16x32_bf16(kf1, qf, s1, 0, 0, 0);
        float mx = -1e30f;
        #pragma unroll
        for (int i = 0; i < 4; ++i) {
            s0[i] *= scale; s1[i] *= scale;
            mx = fmaxf(mx, fmaxf(s0[i], s1[i]));
        }
        mx = fmaxf(mx, __shfl_xor(mx, 16));
        mx = fmaxf(mx, __shfl_xor(mx, 32));
        float mnew = fmaxf(mrun, mx);
        float alpha = __expf(mrun - mnew);
        mrun = mnew;
        lrun *= alpha;
        #pragma unroll
        for (int i = 0; i < 4; ++i) { o0[i] *= alpha; o1[i] *= alpha; }
        float e0[4], e1[4];
        float psum = 0.f;
        #pragma unroll
        for (int i = 0; i < 4; ++i) {
            e0[i] = __expf(s0[i] - mnew);
            e1[i] = __expf(s1[i] - mnew);
            psum += e0[i] + e1[i];
        }
        lrun += psum;
        // pack p (bf16x2) and transpose C-layout -> B-operand layout
        unsigned int t0p0 = pk2(e0[0], e0[1]), t0p1 = pk2(e0[2], e0[3]);
        unsigned int t1p0 = pk2(e1[0], e1[1]), t1p1 = pk2(e1[2], e1[3]);
        unsigned int a0t0 = __shfl((int)t0p0, srcA), a1t0 = __shfl((int)t0p1, srcA);
        unsigned int b0t0 = __shfl((int)t0p0, srcB), b1t0 = __shfl((int)t0p1, srcB);
        unsigned int a0t1 = __shfl((int)t1p0, srcA), a1t1 = __shfl((int)t1p1, srcA);
        unsigned int b0t1 = __shfl((int)t1p0, srcB), b1t1 = __shfl((int)t1p1, srcB);
        union { unsigned int u[4]; bf16x8 v; } pf;
        pf.u[0] = hiq ? a0t1 : a0t0;
        pf.u[1] = hiq ? a1t1 : a1t0;
        pf.u[2] = hiq ? b0t1 : b0t0;
        pf.u[3] = hiq ? b1t1 : b1t0;
        o0 = __builtin_amdgcn_mfma_f32_16x16x32_bf16(vf0, pf.v, o0, 0, 0, 0);
        o1 = __builtin_amdgcn_mfma_f32_16x16x32_bf16(vf1, pf.v, o1, 0, 0, 0);
    }
    float l = lrun;
    l += __shfl_xor(l, 16);
    l += __shfl_xor(l, 32);
    float rinv = 1.0f / l;
    // O^T C-layout: lane holds d = qd*4+i (o0) / 16+qd*4+i (o1), q = r
    #pragma unroll
    for (int i = 0; i < 4; ++i) {
        ob[w][r][qd * 4 + i]      = o0[i] * rinv;
        ob[w][r][16 + qd * 4 + i] = o1[i] * rinv;
    }
    __builtin_amdgcn_s_waitcnt(0);  // drain LDS writes (wave-private region)
    {
        int row = lane >> 2, c8 = (lane & 3) * 8;
        float4 fa = *(const float4*)&ob[w][row][c8];
        float4 fb = *(const float4*)&ob[w][row][c8 + 4];
        uint4 pkd;
        pkd.x = pk2(fa.x, fa.y); pkd.y = pk2(fa.z, fa.w);
        pkd.z = pk2(fb.x, fb.y); pkd.w = pk2(fb.z, fb.w);
        *(uint4*)(msg + ((size_t)(b * N_ + q0 + row)) * H_ + h * DH_ + c8) = pkd;
    }
}

// ---------------- kernel 5: Wo GEMM + residual (128x128 LDS tile) ---------
__global__ __launch_bounds__(256) void out_gemm(
        const unsigned short* __restrict__ msg,
        const unsigned short* __restrict__ WoT,
        const float* __restrict__ x_out,
        float* __restrict__ outx) {
    __shared__ __align__(16) unsigned short As[128 * 32];
    __shared__ __align__(16) unsigned short Bs[128 * 32];
    int t = threadIdx.x;
    int w = t >> 6, lane = t & 63;
    int r = lane & 15, qd = lane >> 4;
    int wm = (w >> 1) * 64, wn = (w & 1) * 64;
    int m0 = blockIdx.y * 128, n0 = blockIdx.x * 128;
    int lrow = lane >> 2, lcol = (lane & 3) * 8;
    floatx4 acc[4][4] = {};
    const unsigned short* gA = msg + (size_t)(m0 + w * 32 + lrow) * H_ + lcol;
    const unsigned short* gB = WoT + (size_t)(n0 + w * 32 + lrow) * H_ + lcol;
    unsigned short* lA = As + (w * 32) * 32;
    unsigned short* lB = Bs + (w * 32) * 32;
    for (int k0 = 0; k0 < H_; k0 += 32) {
        async16(gA + k0,           lA);
        async16(gA + k0 + 16 * H_, lA + 16 * 32);
        async16(gB + k0,           lB);
        async16(gB + k0 + 16 * H_, lB + 16 * 32);
        __syncthreads();
        bf16x8 aF[4], bF[4];
        #pragma unroll
        for (int mt = 0; mt < 4; ++mt)
            aF[mt] = *(const bf16x8*)(As + (wm + mt * 16 + r) * 32 + qd * 8);
        #pragma unroll
        for (int nt = 0; nt < 4; ++nt)
            bF[nt] = *(const bf16x8*)(Bs + (wn + nt * 16 + r) * 32 + qd * 8);
        #pragma unroll
        for (int mt = 0; mt < 4; ++mt)
            #pragma unroll
            for (int nt = 0; nt < 4; ++nt)
                acc[mt][nt] = __builtin_amdgcn_mfma_f32_16x16x32_bf16(aF[mt], bF[nt], acc[mt][nt], 0, 0, 0);
        __syncthreads();
    }
    #pragma unroll
    for (int nt = 0; nt < 4; ++nt) {
        int cg = n0 + wn + nt * 16 + r;
        #pragma unroll
        for (int mt = 0; mt < 4; ++mt) {
            int tok = m0 + wm + mt * 16 + qd * 4;
            #pragma unroll
            for (int i = 0; i < 4; ++i) {
                size_t idx = (size_t)(tok + i) * H_ + cg;
                outx[idx] = x_out[idx] + acc[mt][nt][i];
            }
        }
    }
}

// ---------------- kernel 6: position head  p = msg @ WoP ------------------
__global__ __launch_bounds__(64) void p_kernel(
        const unsigned short* __restrict__ msg, const float* __restrict__ WoP,
        float* __restrict__ outp) {
    int row = blockIdx.x;
    int t = threadIdx.x;
    float a0 = 0.f, a1 = 0.f, a2 = 0.f;
    #pragma unroll
    for (int i = 0; i < 4; ++i) {
        int c = t + 64 * i;
        float v = bf2f(msg[(size_t)row * H_ + c]);
        a0 += v * WoP[c * 3 + 0];
        a1 += v * WoP[c * 3 + 1];
        a2 += v * WoP[c * 3 + 2];
    }
    #pragma unroll
    for (int m = 1; m < 64; m <<= 1) {
        a0 += __shfl_xor(a0, m); a1 += __shfl_xor(a1, m); a2 += __shfl_xor(a2, m);
    }
    if (t == 0) {
        outp[(size_t)row * 3 + 0] = a0;
        outp[(size_t)row * 3 + 1] = a1;
        outp[(size_t)row * 3 + 2] = a2;
    }
}

extern "C" void kernel_launch(void* const* d_in, const int* in_sizes, int n_in,
                              void* d_out, int out_size, void* d_ws, size_t ws_size,
                              hipStream_t stream) {
    const float* x_source = (const float*)d_in[0];
    const float* x_out = (const float*)d_in[2];
    const float* g_s = (const float*)d_in[4];
    const float* b_s = (const float*)d_in[5];
    const float* g_o = (const float*)d_in[6];
    const float* b_o = (const float*)d_in[7];
    const float* Wq = (const float*)d_in[8];
    const float* Wk = (const float*)d_in[9];
    const float* Wv = (const float*)d_in[10];
    const float* Wo = (const float*)d_in[11];
    const float* Wp = (const float*)d_in[12];

    float* outx = (float*)d_out;                  // [BN][256]
    float* outp = outx + (size_t)BN_ * H_;        // [BN][3]

    char* ws = (char*)d_ws;
    unsigned short* f_buf = (unsigned short*)(ws);                 // 16.78 MB
    unsigned short* WcT   = (unsigned short*)(ws + 16777216);      // 786 KB
    unsigned short* WoT   = (unsigned short*)(ws + 17563648);      // 131 KB
    float*          WoP   = (float*)         (ws + 17694720);      // 3 KB
    unsigned short* qb    = (unsigned short*)(ws + 17697792);      // 8.39 MB
    unsigned short* kb    = (unsigned short*)(ws + 26086400);      // 8.39 MB
    unsigned short* vT    = (unsigned short*)(ws + 34475008);      // 8.39 MB
    unsigned short* msg   = (unsigned short*)(ws + 42863616);      // 8.39 MB

    ln_kernel<<<BN_, 64, 0, stream>>>(x_source, x_out, g_s, b_s, g_o, b_o, f_buf);
    pack_w<<<(QKV_ * F_ + 255) / 256, 256, 0, stream>>>(Wq, Wk, Wv, Wo, Wp, WcT, WoT, WoP);
    {
        dim3 g(QKV_ / 128, BN_ / 128);
        qkv_gemm<<<g, 256, 0, stream>>>(f_buf, WcT, qb, kb, vT);
    }
    attn<<<B_ * HEADS_ * (N_ / 64), 256, 0, stream>>>(qb, kb, vT, msg);
    {
        dim3 g(H_ / 128, BN_ / 128);
        out_gemm<<<g, 256, 0, stream>>>(msg, WoT, x_out, outx);
    }
    p_kernel<<<BN_, 64, 0, stream>>>(msg, WoP, outp);
}